// Round 1
// baseline (40.460 us; speedup 1.0000x reference)
//
#include <hip/hip_runtime.h>
#include <math.h>

// Problem constants (from reference): B=2, C=16, D=64, H=128, W=128, K=4
#define SPATIAL (64 * 128 * 128)   // 1048576 = 2^20 voxels per sample
#define NCLS 16
#define NB 2
#define NBLK 2048                  // grid of main kernel; 2048*256*4 voxels == 2*SPATIAL exactly
#define TPB 256

// ---------------- main pass: stream probs/target once, 4 voxels/thread ----------------
__global__ __launch_bounds__(TPB) void bce_main(
    const float* __restrict__ probs,    // [B, C, SPATIAL]
    const int*   __restrict__ target,   // [B, SPATIAL]
    const int*   __restrict__ ann,      // [B, 4]
    float*       __restrict__ partials) // [5][NBLK]: ce, ent_b0, ent_b1, cnt_b0, cnt_b1
{
    // Build per-sample unannotated-class bitmasks (class 0 never annotated as fg)
    unsigned um[NB];
#pragma unroll
    for (int b = 0; b < NB; ++b) {
        unsigned a = 0;
#pragma unroll
        for (int k = 0; k < 4; ++k) {
            int c = ann[b * 4 + k];
            if (c > 0) a |= (1u << c);
        }
        um[b] = ~a & 0xFFFFu;
    }

    const int j = blockIdx.x * TPB + threadIdx.x;  // work item: 4 consecutive voxels
    const int v = j * 4;                           // first voxel id (global)
    const int b = v >> 20;                         // sample index (SPATIAL = 2^20)
    const int s = v & (SPATIAL - 1);               // spatial offset within sample

    const int4 t4 = *reinterpret_cast<const int4*>(target + v);
    const int t[4] = {t4.x, t4.y, t4.z, t4.w};

    const float* pb = probs + (size_t)b * NCLS * SPATIAL + s;
    const unsigned m = um[b];

    float ent[4] = {0.f, 0.f, 0.f, 0.f};  // sum_c p*log2(clamp(p)), log2 units
    float s0[4]  = {0.f, 0.f, 0.f, 0.f};  // background prob = sum over unannotated classes
    float pt[4]  = {0.f, 0.f, 0.f, 0.f};  // prob at target class

#pragma unroll
    for (int c = 0; c < NCLS; ++c) {
        const float4 p4 = *reinterpret_cast<const float4*>(pb + (size_t)c * SPATIAL);
        const float p[4] = {p4.x, p4.y, p4.z, p4.w};
        const bool un = (m >> c) & 1u;
#pragma unroll
        for (int q = 0; q < 4; ++q) {
            const float pc = fminf(fmaxf(p[q], 1e-6f), 0.999999f); // clamp(p, eps, 1-eps)
            ent[q] = fmaf(p[q], __log2f(pc), ent[q]);
            if (un) s0[q] += p[q];
            if (c == t[q]) pt[q] = p[q];
        }
    }

    float ce_sum = 0.f;  // sum of (1-p)^2 * log2(clamp(p))  (negate & *ln2 at finalize)
    float ent_b  = 0.f;
    float cnt_b  = 0.f;
#pragma unroll
    for (int q = 0; q < 4; ++q) {
        const float p  = (t[q] > 0) ? pt[q] : s0[q];
        const float pc = fminf(fmaxf(p, 1e-6f), 0.999999f);
        const float om = 1.f - p;                  // focal term uses UNclamped p
        ce_sum += om * om * __log2f(pc);
        ent_b  += ent[q];
        cnt_b  += (t[q] != 0) ? 1.f : 0.f;
    }

    float vals[5];
    vals[0] = ce_sum;
    vals[1] = (b == 0) ? ent_b : 0.f;
    vals[2] = (b == 1) ? ent_b : 0.f;
    vals[3] = (b == 0) ? cnt_b : 0.f;
    vals[4] = (b == 1) ? cnt_b : 0.f;

    // block reduction: wave shuffle tree, then cross-wave via LDS
    __shared__ float red[5][TPB / 64];
    const int lane = threadIdx.x & 63;
    const int wave = threadIdx.x >> 6;
#pragma unroll
    for (int qq = 0; qq < 5; ++qq) {
        float x = vals[qq];
#pragma unroll
        for (int off = 32; off > 0; off >>= 1)
            x += __shfl_down(x, off, 64);
        if (lane == 0) red[qq][wave] = x;
    }
    __syncthreads();
    if (threadIdx.x == 0) {
#pragma unroll
        for (int qq = 0; qq < 5; ++qq) {
            float x = 0.f;
#pragma unroll
            for (int w = 0; w < TPB / 64; ++w) x += red[qq][w];
            partials[qq * NBLK + blockIdx.x] = x;
        }
    }
}

// ---------------- finalize: deterministic tree-sum of block partials ----------------
__global__ __launch_bounds__(TPB) void bce_final(
    const float* __restrict__ partials, float* __restrict__ out)
{
    __shared__ float red[5][TPB / 64];
    float acc[5] = {0.f, 0.f, 0.f, 0.f, 0.f};
    for (int i = threadIdx.x; i < NBLK; i += TPB) {
#pragma unroll
        for (int qq = 0; qq < 5; ++qq) acc[qq] += partials[qq * NBLK + i];
    }
    const int lane = threadIdx.x & 63;
    const int wave = threadIdx.x >> 6;
#pragma unroll
    for (int qq = 0; qq < 5; ++qq) {
        float x = acc[qq];
#pragma unroll
        for (int off = 32; off > 0; off >>= 1)
            x += __shfl_down(x, off, 64);
        if (lane == 0) red[qq][wave] = x;
    }
    __syncthreads();
    if (threadIdx.x == 0) {
        float ce = 0.f, e0 = 0.f, e1 = 0.f, c0 = 0.f, c1 = 0.f;
#pragma unroll
        for (int w = 0; w < TPB / 64; ++w) {
            ce += red[0][w]; e0 += red[1][w]; e1 += red[2][w];
            c0 += red[3][w]; c1 += red[4][w];
        }
        const float LN2  = 0.69314718055994530942f;
        const float invS = 1.f / (float)SPATIAL;
        const float ent0 = e0 * LN2 * invS;             // mean_spatial sum_c p ln p, sample 0
        const float ent1 = e1 * LN2 * invS;
        const float m0   = (c0 == 0.f) ? 3.f : 1.f;     // all_bg -> MULT_UNLABELED
        const float m1   = (c1 == 0.f) ? 3.f : 1.f;
        const float reg  = -(m0 * ent0 + m1 * ent1) * 0.5f;   // / batch
        const float cef  = -(ce * LN2) / (float)(NB * SPATIAL);
        out[0] = cef;
        out[1] = reg;
    }
}

extern "C" void kernel_launch(void* const* d_in, const int* in_sizes, int n_in,
                              void* d_out, int out_size, void* d_ws, size_t ws_size,
                              hipStream_t stream) {
    const float* probs  = (const float*)d_in[0];
    const int*   target = (const int*)d_in[1];
    const int*   ann    = (const int*)d_in[2];
    float*       out    = (float*)d_out;
    float*       partials = (float*)d_ws;   // 5 * NBLK * 4 B = 40 KiB

    bce_main<<<NBLK, TPB, 0, stream>>>(probs, target, ann, partials);
    bce_final<<<1, TPB, 0, stream>>>(partials, out);
}